// Round 5
// baseline (176.154 us; speedup 1.0000x reference)
//
#include <hip/hip_runtime.h>

#define NP   1024
#define DIM  768
#define NH   12
#define HD   64
#define TQ   2304
#define EPS  1e-6f

typedef __attribute__((ext_vector_type(8))) short bf16x8;
typedef __attribute__((ext_vector_type(4))) float f32x4;

#define MFMA(a, b, c) __builtin_amdgcn_mfma_f32_16x16x32_bf16((a), (b), (c), 0, 0, 0)

__device__ __forceinline__ unsigned short f2b(float x) {       // fp32 -> bf16 RNE
    unsigned int u = __builtin_bit_cast(unsigned int, x);
    u = (u + 0x7fffu + ((u >> 16) & 1u)) >> 16;
    return (unsigned short)u;
}
__device__ __forceinline__ float b2f(unsigned short h) {
    unsigned int u = ((unsigned int)h) << 16;
    return __builtin_bit_cast(float, u);
}
#if __has_builtin(__builtin_amdgcn_cvt_pk_bf16_f32)
typedef __attribute__((ext_vector_type(2))) __bf16 bf16x2t;
__device__ __forceinline__ unsigned int pk2(float lo, float hi) {
    bf16x2t v = __builtin_amdgcn_cvt_pk_bf16_f32(lo, hi);
    return __builtin_bit_cast(unsigned int, v);
}
#else
__device__ __forceinline__ unsigned int pk2(float lo, float hi) {
    return (unsigned int)f2b(lo) | ((unsigned int)f2b(hi) << 16);
}
#endif
__device__ __forceinline__ void gld16(const void* g, void* l) { // 16B global -> LDS
    __builtin_amdgcn_global_load_lds((const __attribute__((address_space(1))) unsigned int*)g,
                                     (__attribute__((address_space(3))) unsigned int*)l,
                                     16, 0, 0);
}

// --------------------------------------------------------------------------
// fused prep: convert x -> bf16 ; transpose W_qkv, W_out -> bf16 ;
// M2 = 0.1*mask^T + I -> bf16 (graphmix residual folded into the operator)
// --------------------------------------------------------------------------
__global__ __launch_bounds__(256) void k_prep(const float* __restrict__ x,
                                              const float* __restrict__ W_qkv,
                                              const float* __restrict__ W_out,
                                              const float* __restrict__ mask,
                                              unsigned short* __restrict__ xb,
                                              unsigned short* __restrict__ WqkvT,
                                              unsigned short* __restrict__ WoutT,
                                              unsigned short* __restrict__ M2) {
    __shared__ float buf[64][65];
    const int bx = blockIdx.x, t = threadIdx.x;
    if (bx < 1536) {                       // convert x (4096*768 elems, 8/thread)
        const int i = bx * 256 + t;
        const float4* p = (const float4*)x + (size_t)i * 2;
        float4 a = p[0], b = p[1];
        alignas(16) unsigned short o[8] = {f2b(a.x), f2b(a.y), f2b(a.z), f2b(a.w),
                                           f2b(b.x), f2b(b.y), f2b(b.z), f2b(b.w)};
        *(uint4*)(xb + (size_t)i * 8) = *(const uint4*)o;
        return;
    }
    const float* in; unsigned short* outp; int R, C, ct, rt; bool isMask = false;
    if (bx < 1968)      { int q = bx - 1536; in = W_qkv; outp = WqkvT; R = 768;  C = 2304; ct = q % 36; rt = q / 36; }
    else if (bx < 2112) { int q = bx - 1968; in = W_out; outp = WoutT; R = 768;  C = 768;  ct = q % 12; rt = q / 12; }
    else                { int q = bx - 2112; in = mask;  outp = M2;    R = 1024; C = 1024; ct = q % 16; rt = q / 16; isMask = true; }
    const int r0 = rt * 64, c0 = ct * 64;
    const int rr = t >> 4, cc = (t & 15) * 4;
    #pragma unroll
    for (int p = 0; p < 4; ++p) {
        float4 v = *(const float4*)(in + (size_t)(r0 + p * 16 + rr) * C + c0 + cc);
        buf[p * 16 + rr][cc + 0] = v.x; buf[p * 16 + rr][cc + 1] = v.y;
        buf[p * 16 + rr][cc + 2] = v.z; buf[p * 16 + rr][cc + 3] = v.w;
    }
    __syncthreads();
    const int oc = t >> 2, orr = (t & 3) * 16;
    alignas(16) unsigned short tmp[16];
    if (isMask) {
        #pragma unroll
        for (int j = 0; j < 16; ++j) {
            float v = 0.1f * buf[orr + j][oc] + ((c0 + oc) == (r0 + orr + j) ? 1.f : 0.f);
            tmp[j] = f2b(v);
        }
    } else {
        #pragma unroll
        for (int j = 0; j < 16; ++j) tmp[j] = f2b(buf[orr + j][oc]);
    }
    unsigned short* dst = outp + (size_t)(c0 + oc) * R + r0 + orr;
    *(uint4*)dst = *(const uint4*)tmp;
    *(uint4*)(dst + 8) = *(const uint4*)(tmp + 8);
}

// --------------------------------------------------------------------------
// gemm1: qkv = xb @ WqkvT^T; direct fragment stores to transposed layout
// T[slot*48 + b*12 + h][d][np] (relu+eps fused on q,k slots).
// --------------------------------------------------------------------------
__global__ __launch_bounds__(256) void k_gemm1(const unsigned short* __restrict__ A,
                                               const unsigned short* __restrict__ Bt,
                                               unsigned short* __restrict__ T) {
    __shared__ unsigned short As[128][32];
    __shared__ unsigned short Bs[128][32];
    const int tid = threadIdx.x, w = tid >> 6, l = tid & 63;
    const int m0 = blockIdx.y * 128, n0 = blockIdx.x * 128;
    const int wm = (w >> 1) * 64, wn = (w & 1) * 64;
    const int quad = l >> 4, col = l & 15;
    const int lr = l >> 2, lc = (l & 3) * 8;

    f32x4 acc[4][4] = {};
    for (int k0 = 0; k0 < DIM; k0 += 32) {
        gld16(A + (size_t)(m0 + w * 32 + lr) * DIM + k0 + lc, &As[w * 32][0]);
        gld16(A + (size_t)(m0 + w * 32 + 16 + lr) * DIM + k0 + lc, &As[w * 32 + 16][0]);
        gld16(Bt + (size_t)(n0 + w * 32 + lr) * DIM + k0 + lc, &Bs[w * 32][0]);
        gld16(Bt + (size_t)(n0 + w * 32 + 16 + lr) * DIM + k0 + lc, &Bs[w * 32 + 16][0]);
        __syncthreads();
        bf16x8 a[4], b[4];
        #pragma unroll
        for (int i = 0; i < 4; ++i) a[i] = *(const bf16x8*)&As[wm + i * 16 + col][quad * 8];
        #pragma unroll
        for (int j = 0; j < 4; ++j) b[j] = *(const bf16x8*)&Bs[wn + j * 16 + col][quad * 8];
        #pragma unroll
        for (int i = 0; i < 4; ++i)
            #pragma unroll
            for (int j = 0; j < 4; ++j)
                acc[i][j] = MFMA(a[i], b[j], acc[i][j]);
        __syncthreads();
    }

    const int cgb = n0 + wn;                    // multiple of 64 -> fixed slot,h
    const int slot = cgb / DIM;
    const int h = (cgb % DIM) >> 6;
    const bool act = (slot < 2);
    const int sh = slot * 48 + (m0 >> 10) * NH + h;
    const int npb = (m0 & 1023) + wm + quad * 4;
    #pragma unroll
    for (int j = 0; j < 4; ++j) {
        unsigned short* dcol = T + ((size_t)(sh * HD + j * 16 + col)) * NP + npb;
        #pragma unroll
        for (int i = 0; i < 4; ++i) {
            float v0 = acc[i][j][0], v1 = acc[i][j][1], v2 = acc[i][j][2], v3 = acc[i][j][3];
            if (act) {
                v0 = fmaxf(v0, 0.f) + EPS; v1 = fmaxf(v1, 0.f) + EPS;
                v2 = fmaxf(v2, 0.f) + EPS; v3 = fmaxf(v3, 0.f) + EPS;
            }
            uint2 o; o.x = pk2(v0, v1); o.y = pk2(v2, v3);
            *(uint2*)(dcol + i * 16) = o;
        }
    }
}

// --------------------------------------------------------------------------
// graphmix: pure banded GEMM  q2[m][d] = sum_n M2[m][n] * f(n,d)
// (M2 = 0.1*mask^T + I, so the residual f-term is folded in).
// Operands arranged so D rows = d -> packed 8B stores to q2[m][d].
// Band: 64-wide n-chunks c in [mt-3, mt+3] (M2 zero outside).
// --------------------------------------------------------------------------
__global__ __launch_bounds__(256) void k_graphmix(const unsigned short* __restrict__ M2,
                                                  const unsigned short* __restrict__ T,
                                                  unsigned short* __restrict__ q2) {
    const int bh = blockIdx.y, mt = blockIdx.x;
    const int m0 = mt * 64;
    __shared__ unsigned short M2s[2][64][32], Fq[2][64][32], Fk[2][64][32];
    const int tid = threadIdx.x, w = tid >> 6, l = tid & 63;
    const int quad = l >> 4, col = l & 15;
    const int lr = l >> 2, lc = (l & 3) * 8;
    const unsigned short* Tq = T + (size_t)bh * HD * NP;
    const unsigned short* Tk = T + (size_t)(48 + bh) * HD * NP;

    f32x4 accq[4] = {}, acck[4] = {};
    const int c0 = max(0, mt - 3), c1 = min(15, mt + 3);
    for (int c = c0; c <= c1; ++c) {
        const int nc = c * 64;
        __syncthreads();
        #pragma unroll
        for (int hh = 0; hh < 2; ++hh) {
            gld16(M2 + (size_t)(m0 + w * 16 + lr) * NP + nc + hh * 32 + lc, &M2s[hh][w * 16][0]);
            gld16(Tq + (size_t)(w * 16 + lr) * NP + nc + hh * 32 + lc, &Fq[hh][w * 16][0]);
            gld16(Tk + (size_t)(w * 16 + lr) * NP + nc + hh * 32 + lc, &Fk[hh][w * 16][0]);
        }
        __syncthreads();
        #pragma unroll
        for (int ks = 0; ks < 2; ++ks) {
            bf16x8 bm = *(const bf16x8*)&M2s[ks][w * 16 + col][quad * 8];   // B: cols=m
            #pragma unroll
            for (int dt = 0; dt < 4; ++dt) {
                bf16x8 aq = *(const bf16x8*)&Fq[ks][dt * 16 + col][quad * 8]; // A: rows=d
                bf16x8 ak = *(const bf16x8*)&Fk[ks][dt * 16 + col][quad * 8];
                accq[dt] = MFMA(aq, bm, accq[dt]);
                acck[dt] = MFMA(ak, bm, acck[dt]);
            }
        }
    }
    // D[row=d=dt*16+quad*4+r][col=m=w*16+col] -> q2[m][d], 4 consecutive d packed
    unsigned short* q2q = q2 + ((size_t)bh * NP + m0 + w * 16 + col) * HD;
    unsigned short* q2k = q2 + ((size_t)(48 + bh) * NP + m0 + w * 16 + col) * HD;
    #pragma unroll
    for (int dt = 0; dt < 4; ++dt) {
        const int d0 = dt * 16 + quad * 4;
        uint2 oq; oq.x = pk2(accq[dt][0], accq[dt][1]); oq.y = pk2(accq[dt][2], accq[dt][3]);
        uint2 ok; ok.x = pk2(acck[dt][0], acck[dt][1]); ok.y = pk2(acck[dt][2], acck[dt][3]);
        *(uint2*)(q2q + d0) = oq;
        *(uint2*)(q2k + d0) = ok;
    }
}

// --------------------------------------------------------------------------
// attention: 128-row Q tiles; band m-tiles [2nt2-3, 2nt2+4].
// S round-trip via n-pair-interleaved dwords: Ss2[n>>1][m] = pk(bf16 n_even,
// bf16 n_odd) -> 16 cvt_pk + 16 b32 LDS writes per m-tile (was 128 VALU +
// 32 scalar b16); A-frags rebuilt with 2x b128 + 4x v_perm.
// --------------------------------------------------------------------------
__global__ __launch_bounds__(256) void k_attn(const unsigned short* __restrict__ q2,
                                              const unsigned short* __restrict__ T,
                                              const float* __restrict__ mask,
                                              unsigned short* __restrict__ attnb) {
    const int bh = blockIdx.y, b = bh / NH, h = bh % NH;
    const int nt2 = blockIdx.x, n0 = nt2 * 128;
    __shared__ unsigned short Qs[2][128][32];
    __shared__ unsigned short Ks[2][64][32];
    __shared__ unsigned short VT[2][64][32];
    __shared__ unsigned int Ss2[64][68];          // [n>>1][m] pitch 68 dwords
    __shared__ float rowz[128];
    const int tid = threadIdx.x, w = tid >> 6, l = tid & 63;
    const int quad = l >> 4, col = l & 15;
    const int lr = l >> 2, lc = (l & 3) * 8;

    const unsigned short* qb = q2 + ((size_t)bh * NP + n0) * HD;
    const unsigned short* kb = q2 + (size_t)(48 + bh) * NP * HD;
    const unsigned short* vtb = T + (size_t)(96 + bh) * HD * NP;

    #pragma unroll
    for (int hh = 0; hh < 2; ++hh)
        #pragma unroll
        for (int c = 0; c < 2; ++c)
            gld16(qb + (size_t)(w * 32 + c * 16 + lr) * HD + hh * 32 + lc,
                  &Qs[hh][w * 32 + c * 16][0]);

    f32x4 oacc[2][4] = {};
    float racc[2][4] = {};
    const int mlo = max(0, 2 * nt2 - 3), mhi = min(15, 2 * nt2 + 4);
    const unsigned int sel = (col & 1) ? 0x07060302u : 0x05040100u;

    for (int mt = mlo; mt <= mhi; ++mt) {
        const int m0 = mt * 64;
        float mreg[2][4][4];               // prefetch mask into regs pre-barrier
        #pragma unroll
        for (int rg = 0; rg < 2; ++rg)
            #pragma unroll
            for (int mtt = 0; mtt < 4; ++mtt)
                #pragma unroll
                for (int r = 0; r < 4; ++r)
                    mreg[rg][mtt][r] = mask[(size_t)(n0 + (w * 2 + rg) * 16 + quad * 4 + r) * NP
                                            + m0 + mtt * 16 + col];
        __syncthreads();                   // prior iter's Ks/VT/Ss2 consumers done
        #pragma unroll
        for (int hh = 0; hh < 2; ++hh) {
            gld16(kb + (size_t)(m0 + w * 16 + lr) * HD + hh * 32 + lc, &Ks[hh][w * 16][0]);
            gld16(vtb + (size_t)(w * 16 + lr) * NP + m0 + hh * 32 + lc, &VT[hh][w * 16][0]);
        }
        __syncthreads();

        f32x4 s[2][4] = {};
        #pragma unroll
        for (int ks = 0; ks < 2; ++ks) {
            bf16x8 bk[4];
            #pragma unroll
            for (int mtt = 0; mtt < 4; ++mtt) bk[mtt] = *(const bf16x8*)&Ks[ks][mtt * 16 + col][quad * 8];
            #pragma unroll
            for (int rg = 0; rg < 2; ++rg) {
                bf16x8 aq = *(const bf16x8*)&Qs[ks][(w * 2 + rg) * 16 + col][quad * 8];
                #pragma unroll
                for (int mtt = 0; mtt < 4; ++mtt) s[rg][mtt] = MFMA(aq, bk[mtt], s[rg][mtt]);
            }
        }
        #pragma unroll
        for (int rg = 0; rg < 2; ++rg) {
            const int npr = (w * 2 + rg) * 8 + quad * 2;
            #pragma unroll
            for (int mtt = 0; mtt < 4; ++mtt) {
                float v0 = s[rg][mtt][0] * mreg[rg][mtt][0];
                float v1 = s[rg][mtt][1] * mreg[rg][mtt][1];
                float v2 = s[rg][mtt][2] * mreg[rg][mtt][2];
                float v3 = s[rg][mtt][3] * mreg[rg][mtt][3];
                racc[rg][0] += v0; racc[rg][1] += v1;
                racc[rg][2] += v2; racc[rg][3] += v3;
                Ss2[npr][mtt * 16 + col]     = pk2(v0, v1);
                Ss2[npr + 1][mtt * 16 + col] = pk2(v2, v3);
            }
        }
        __syncthreads();
        #pragma unroll
        for (int ks = 0; ks < 2; ++ks) {
            bf16x8 bv[4];
            #pragma unroll
            for (int dt = 0; dt < 4; ++dt) bv[dt] = *(const bf16x8*)&VT[ks][dt * 16 + col][quad * 8];
            #pragma unroll
            for (int rg = 0; rg < 2; ++rg) {
                const unsigned int* rp = &Ss2[(w * 2 + rg) * 8 + (col >> 1)][ks * 32 + quad * 8];
                uint4 U  = *(const uint4*)rp;
                uint4 U2 = *(const uint4*)(rp + 4);
                uint4 fr;
                fr.x = __builtin_amdgcn_perm(U.y,  U.x,  sel);
                fr.y = __builtin_amdgcn_perm(U.w,  U.z,  sel);
                fr.z = __builtin_amdgcn_perm(U2.y, U2.x, sel);
                fr.w = __builtin_amdgcn_perm(U2.w, U2.z, sel);
                bf16x8 as = __builtin_bit_cast(bf16x8, fr);
                #pragma unroll
                for (int dt = 0; dt < 4; ++dt) oacc[rg][dt] = MFMA(as, bv[dt], oacc[rg][dt]);
            }
        }
    }

    #pragma unroll
    for (int rg = 0; rg < 2; ++rg)
        #pragma unroll
        for (int r = 0; r < 4; ++r) {
            float v = racc[rg][r];
            v += __shfl_xor(v, 1); v += __shfl_xor(v, 2);
            v += __shfl_xor(v, 4); v += __shfl_xor(v, 8);
            if (col == 0) rowz[(w * 2 + rg) * 16 + quad * 4 + r] = v;
        }
    __syncthreads();
    #pragma unroll
    for (int rg = 0; rg < 2; ++rg)
        #pragma unroll
        for (int r = 0; r < 4; ++r) {
            const int nl = (w * 2 + rg) * 16 + quad * 4 + r;
            const float z = 1.f / (rowz[nl] + EPS);
            #pragma unroll
            for (int dt = 0; dt < 4; ++dt)
                attnb[(size_t)(b * NP + n0 + nl) * DIM + h * HD + dt * 16 + col] =
                    f2b(oacc[rg][dt][r] * z);
        }
}

// --------------------------------------------------------------------------
// gemm2: out = attnb @ WoutT^T + b_out (fp32). 128m x 64n tiles, grid 12x32
// = 384 blocks; 8 MFMA : 3 gld per wave-iter.
// --------------------------------------------------------------------------
__global__ __launch_bounds__(256) void k_gemm2(const unsigned short* __restrict__ A,
                                               const unsigned short* __restrict__ Bt,
                                               const float* __restrict__ bias,
                                               float* __restrict__ C) {
    __shared__ unsigned short As[128][32];
    __shared__ unsigned short Bs[64][32];
    const int tid = threadIdx.x, w = tid >> 6, l = tid & 63;
    const int m0 = blockIdx.y * 128, n0 = blockIdx.x * 64;
    const int wm = (w >> 1) * 64, wn = (w & 1) * 32;
    const int quad = l >> 4, col = l & 15;
    const int lr = l >> 2, lc = (l & 3) * 8;

    f32x4 acc[4][2] = {};
    for (int k0 = 0; k0 < DIM; k0 += 32) {
        gld16(A + (size_t)(m0 + w * 32 + lr) * DIM + k0 + lc, &As[w * 32][0]);
        gld16(A + (size_t)(m0 + w * 32 + 16 + lr) * DIM + k0 + lc, &As[w * 32 + 16][0]);
        gld16(Bt + (size_t)(n0 + w * 16 + lr) * DIM + k0 + lc, &Bs[w * 16][0]);
        __syncthreads();
        bf16x8 a[4], b[2];
        #pragma unroll
        for (int i = 0; i < 4; ++i) a[i] = *(const bf16x8*)&As[wm + i * 16 + col][quad * 8];
        #pragma unroll
        for (int j = 0; j < 2; ++j) b[j] = *(const bf16x8*)&Bs[wn + j * 16 + col][quad * 8];
        #pragma unroll
        for (int i = 0; i < 4; ++i)
            #pragma unroll
            for (int j = 0; j < 2; ++j)
                acc[i][j] = MFMA(a[i], b[j], acc[i][j]);
        __syncthreads();
    }
    #pragma unroll
    for (int i = 0; i < 4; ++i)
        #pragma unroll
        for (int j = 0; j < 2; ++j) {
            const int n = n0 + wn + j * 16 + col;
            #pragma unroll
            for (int r = 0; r < 4; ++r) {
                const int m = m0 + wm + i * 16 + quad * 4 + r;
                C[(size_t)m * DIM + n] = acc[i][j][r] + bias[n];
            }
        }
}

// --------------------------------------------------------------------------
extern "C" void kernel_launch(void* const* d_in, const int* in_sizes, int n_in,
                              void* d_out, int out_size, void* d_ws, size_t ws_size,
                              hipStream_t stream) {
    (void)in_sizes; (void)n_in; (void)out_size; (void)ws_size;
    const float* x     = (const float*)d_in[0];
    const float* W_qkv = (const float*)d_in[1];
    const float* W_out = (const float*)d_in[2];
    const float* b_out = (const float*)d_in[3];
    const float* mask  = (const float*)d_in[4];
    float* out = (float*)d_out;

    unsigned short* p = (unsigned short*)d_ws;
    unsigned short* xb    = p; p += (size_t)4096 * DIM;
    unsigned short* WqkvT = p; p += (size_t)TQ * DIM;
    unsigned short* WoutT = p; p += (size_t)DIM * DIM;
    unsigned short* M2    = p; p += (size_t)NP * NP;
    unsigned short* T     = p; p += (size_t)3 * 48 * HD * NP;
    unsigned short* q2    = p; p += (size_t)2 * 48 * NP * HD;
    unsigned short* attnb = p; p += (size_t)4096 * DIM;

    k_prep<<<dim3(2368), 256, 0, stream>>>(x, W_qkv, W_out, mask, xb, WqkvT, WoutT, M2);
    k_gemm1<<<dim3(TQ / 128, 4096 / 128), 256, 0, stream>>>(xb, WqkvT, T);
    k_graphmix<<<dim3(NP / 64, 48), 256, 0, stream>>>(M2, T, q2);
    k_attn<<<dim3(NP / 128, 48), 256, 0, stream>>>(q2, T, mask, attnb);
    k_gemm2<<<dim3(DIM / 64, 4096 / 128), 256, 0, stream>>>(attnb, WoutT, b_out, out);
}

// Round 6
// 163.461 us; speedup vs baseline: 1.0777x; 1.0777x over previous
//
#include <hip/hip_runtime.h>

#define NP   1024
#define DIM  768
#define NH   12
#define HD   64
#define TQ   2304
#define EPS  1e-6f

typedef __attribute__((ext_vector_type(8))) short bf16x8;
typedef __attribute__((ext_vector_type(4))) float f32x4;

#define MFMA(a, b, c) __builtin_amdgcn_mfma_f32_16x16x32_bf16((a), (b), (c), 0, 0, 0)

__device__ __forceinline__ unsigned short f2b(float x) {       // fp32 -> bf16 RNE
    unsigned int u = __builtin_bit_cast(unsigned int, x);
    u = (u + 0x7fffu + ((u >> 16) & 1u)) >> 16;
    return (unsigned short)u;
}
__device__ __forceinline__ float b2f(unsigned short h) {
    unsigned int u = ((unsigned int)h) << 16;
    return __builtin_bit_cast(float, u);
}
#if __has_builtin(__builtin_amdgcn_cvt_pk_bf16_f32)
typedef __attribute__((ext_vector_type(2))) __bf16 bf16x2t;
__device__ __forceinline__ unsigned int pk2(float lo, float hi) {
    bf16x2t v = __builtin_amdgcn_cvt_pk_bf16_f32(lo, hi);
    return __builtin_bit_cast(unsigned int, v);
}
#else
__device__ __forceinline__ unsigned int pk2(float lo, float hi) {
    return (unsigned int)f2b(lo) | ((unsigned int)f2b(hi) << 16);
}
#endif
__device__ __forceinline__ void gld16(const void* g, void* l) { // 16B global -> LDS
    __builtin_amdgcn_global_load_lds((const __attribute__((address_space(1))) unsigned int*)g,
                                     (__attribute__((address_space(3))) unsigned int*)l,
                                     16, 0, 0);
}

// --------------------------------------------------------------------------
// fused prep: convert x -> bf16 ; transpose W_qkv, W_out -> bf16 ;
// M2 = 0.1*mask^T + I -> bf16 (graphmix residual folded into the operator)
// --------------------------------------------------------------------------
__global__ __launch_bounds__(256) void k_prep(const float* __restrict__ x,
                                              const float* __restrict__ W_qkv,
                                              const float* __restrict__ W_out,
                                              const float* __restrict__ mask,
                                              unsigned short* __restrict__ xb,
                                              unsigned short* __restrict__ WqkvT,
                                              unsigned short* __restrict__ WoutT,
                                              unsigned short* __restrict__ M2) {
    __shared__ float buf[64][65];
    const int bx = blockIdx.x, t = threadIdx.x;
    if (bx < 1536) {                       // convert x (4096*768 elems, 8/thread)
        const int i = bx * 256 + t;
        const float4* p = (const float4*)x + (size_t)i * 2;
        float4 a = p[0], b = p[1];
        alignas(16) unsigned short o[8] = {f2b(a.x), f2b(a.y), f2b(a.z), f2b(a.w),
                                           f2b(b.x), f2b(b.y), f2b(b.z), f2b(b.w)};
        *(uint4*)(xb + (size_t)i * 8) = *(const uint4*)o;
        return;
    }
    const float* in; unsigned short* outp; int R, C, ct, rt; bool isMask = false;
    if (bx < 1968)      { int q = bx - 1536; in = W_qkv; outp = WqkvT; R = 768;  C = 2304; ct = q % 36; rt = q / 36; }
    else if (bx < 2112) { int q = bx - 1968; in = W_out; outp = WoutT; R = 768;  C = 768;  ct = q % 12; rt = q / 12; }
    else                { int q = bx - 2112; in = mask;  outp = M2;    R = 1024; C = 1024; ct = q % 16; rt = q / 16; isMask = true; }
    const int r0 = rt * 64, c0 = ct * 64;
    const int rr = t >> 4, cc = (t & 15) * 4;
    #pragma unroll
    for (int p = 0; p < 4; ++p) {
        float4 v = *(const float4*)(in + (size_t)(r0 + p * 16 + rr) * C + c0 + cc);
        buf[p * 16 + rr][cc + 0] = v.x; buf[p * 16 + rr][cc + 1] = v.y;
        buf[p * 16 + rr][cc + 2] = v.z; buf[p * 16 + rr][cc + 3] = v.w;
    }
    __syncthreads();
    const int oc = t >> 2, orr = (t & 3) * 16;
    alignas(16) unsigned short tmp[16];
    if (isMask) {
        #pragma unroll
        for (int j = 0; j < 16; ++j) {
            float v = 0.1f * buf[orr + j][oc] + ((c0 + oc) == (r0 + orr + j) ? 1.f : 0.f);
            tmp[j] = f2b(v);
        }
    } else {
        #pragma unroll
        for (int j = 0; j < 16; ++j) tmp[j] = f2b(buf[orr + j][oc]);
    }
    unsigned short* dst = outp + (size_t)(c0 + oc) * R + r0 + orr;
    *(uint4*)dst = *(const uint4*)tmp;
    *(uint4*)(dst + 8) = *(const uint4*)(tmp + 8);
}

// --------------------------------------------------------------------------
// gemm1: qkv = xb @ WqkvT^T, 512 threads (8 waves) per block for 2x resident
// waves vs 256-thr (latency-bound fix). 128x128 tile, BK=32, m97 LDS geometry.
// XCD-swizzled 1D grid: each XCD works a 4-m-strip supertile (L2 locality).
// Epilogue: direct packed stores to T[slot*48+b*12+h][d][np], relu+eps on q,k.
// --------------------------------------------------------------------------
__global__ __launch_bounds__(512) void k_gemm1(const unsigned short* __restrict__ A,
                                               const unsigned short* __restrict__ Bt,
                                               unsigned short* __restrict__ T) {
    __shared__ unsigned short As[128][32];
    __shared__ unsigned short Bs[128][32];
    const int tid = threadIdx.x, w = tid >> 6, l = tid & 63;
    const int bid = blockIdx.x;                 // 576 blocks
    const int mstrip = (bid & 7) * 4 + ((bid >> 3) & 3);   // [0,32)
    const int nstrip = bid >> 5;                           // [0,18)
    const int m0 = mstrip * 128, n0 = nstrip * 128;
    const int wm = (w & 3) * 32, wn = (w >> 2) * 64;
    const int quad = l >> 4, col = l & 15;
    const int lr = l >> 2, lc = (l & 3) * 8;

    f32x4 acc[2][4] = {};
    for (int k0 = 0; k0 < DIM; k0 += 32) {
        gld16(A + (size_t)(m0 + w * 16 + lr) * DIM + k0 + lc, &As[w * 16][0]);
        gld16(Bt + (size_t)(n0 + w * 16 + lr) * DIM + k0 + lc, &Bs[w * 16][0]);
        __syncthreads();
        bf16x8 a[2], b[4];
        #pragma unroll
        for (int i = 0; i < 2; ++i) a[i] = *(const bf16x8*)&As[wm + i * 16 + col][quad * 8];
        #pragma unroll
        for (int j = 0; j < 4; ++j) b[j] = *(const bf16x8*)&Bs[wn + j * 16 + col][quad * 8];
        #pragma unroll
        for (int i = 0; i < 2; ++i)
            #pragma unroll
            for (int j = 0; j < 4; ++j)
                acc[i][j] = MFMA(a[i], b[j], acc[i][j]);
        __syncthreads();
    }

    const int cgb = n0 + wn;                    // multiple of 64 -> fixed slot,h
    const int slot = cgb / DIM;
    const int h = (cgb % DIM) >> 6;
    const bool act = (slot < 2);
    const int sh = slot * 48 + (m0 >> 10) * NH + h;
    const int npb = (m0 & 1023) + wm + quad * 4;
    #pragma unroll
    for (int j = 0; j < 4; ++j) {
        unsigned short* dcol = T + ((size_t)(sh * HD + j * 16 + col)) * NP + npb;
        #pragma unroll
        for (int i = 0; i < 2; ++i) {
            float v0 = acc[i][j][0], v1 = acc[i][j][1], v2 = acc[i][j][2], v3 = acc[i][j][3];
            if (act) {
                v0 = fmaxf(v0, 0.f) + EPS; v1 = fmaxf(v1, 0.f) + EPS;
                v2 = fmaxf(v2, 0.f) + EPS; v3 = fmaxf(v3, 0.f) + EPS;
            }
            uint2 o; o.x = pk2(v0, v1); o.y = pk2(v2, v3);
            *(uint2*)(dcol + i * 16) = o;
        }
    }
}

// --------------------------------------------------------------------------
// graphmix: pure banded GEMM  q2[m][d] = sum_n M2[m][n] * f(n,d)
// (M2 = 0.1*mask^T + I). D rows = d -> packed 8B stores to q2[m][d].
// --------------------------------------------------------------------------
__global__ __launch_bounds__(256) void k_graphmix(const unsigned short* __restrict__ M2,
                                                  const unsigned short* __restrict__ T,
                                                  unsigned short* __restrict__ q2) {
    const int bh = blockIdx.y, mt = blockIdx.x;
    const int m0 = mt * 64;
    __shared__ unsigned short M2s[2][64][32], Fq[2][64][32], Fk[2][64][32];
    const int tid = threadIdx.x, w = tid >> 6, l = tid & 63;
    const int quad = l >> 4, col = l & 15;
    const int lr = l >> 2, lc = (l & 3) * 8;
    const unsigned short* Tq = T + (size_t)bh * HD * NP;
    const unsigned short* Tk = T + (size_t)(48 + bh) * HD * NP;

    f32x4 accq[4] = {}, acck[4] = {};
    const int c0 = max(0, mt - 3), c1 = min(15, mt + 3);
    for (int c = c0; c <= c1; ++c) {
        const int nc = c * 64;
        __syncthreads();
        #pragma unroll
        for (int hh = 0; hh < 2; ++hh) {
            gld16(M2 + (size_t)(m0 + w * 16 + lr) * NP + nc + hh * 32 + lc, &M2s[hh][w * 16][0]);
            gld16(Tq + (size_t)(w * 16 + lr) * NP + nc + hh * 32 + lc, &Fq[hh][w * 16][0]);
            gld16(Tk + (size_t)(w * 16 + lr) * NP + nc + hh * 32 + lc, &Fk[hh][w * 16][0]);
        }
        __syncthreads();
        #pragma unroll
        for (int ks = 0; ks < 2; ++ks) {
            bf16x8 bm = *(const bf16x8*)&M2s[ks][w * 16 + col][quad * 8];   // B: cols=m
            #pragma unroll
            for (int dt = 0; dt < 4; ++dt) {
                bf16x8 aq = *(const bf16x8*)&Fq[ks][dt * 16 + col][quad * 8]; // A: rows=d
                bf16x8 ak = *(const bf16x8*)&Fk[ks][dt * 16 + col][quad * 8];
                accq[dt] = MFMA(aq, bm, accq[dt]);
                acck[dt] = MFMA(ak, bm, acck[dt]);
            }
        }
    }
    unsigned short* q2q = q2 + ((size_t)bh * NP + m0 + w * 16 + col) * HD;
    unsigned short* q2k = q2 + ((size_t)(48 + bh) * NP + m0 + w * 16 + col) * HD;
    #pragma unroll
    for (int dt = 0; dt < 4; ++dt) {
        const int d0 = dt * 16 + quad * 4;
        uint2 oq; oq.x = pk2(accq[dt][0], accq[dt][1]); oq.y = pk2(accq[dt][2], accq[dt][3]);
        uint2 ok; ok.x = pk2(acck[dt][0], acck[dt][1]); ok.y = pk2(acck[dt][2], acck[dt][3]);
        *(uint2*)(q2q + d0) = oq;
        *(uint2*)(q2k + d0) = ok;
    }
}

// --------------------------------------------------------------------------
// attention: 128-row Q tiles; band m-tiles [2nt2-3, 2nt2+4]; mask register
// loads issued BETWEEN gld16 issue and the barrier (overlap staging latency).
// S round-trip via n-pair-interleaved dwords + v_perm rebuild.
// --------------------------------------------------------------------------
__global__ __launch_bounds__(256) void k_attn(const unsigned short* __restrict__ q2,
                                              const unsigned short* __restrict__ T,
                                              const float* __restrict__ mask,
                                              unsigned short* __restrict__ attnb) {
    const int bh = blockIdx.y, b = bh / NH, h = bh % NH;
    const int nt2 = blockIdx.x, n0 = nt2 * 128;
    __shared__ unsigned short Qs[2][128][32];
    __shared__ unsigned short Ks[2][64][32];
    __shared__ unsigned short VT[2][64][32];
    __shared__ unsigned int Ss2[64][68];          // [n>>1][m] pitch 68 dwords
    __shared__ float rowz[128];
    const int tid = threadIdx.x, w = tid >> 6, l = tid & 63;
    const int quad = l >> 4, col = l & 15;
    const int lr = l >> 2, lc = (l & 3) * 8;

    const unsigned short* qb = q2 + ((size_t)bh * NP + n0) * HD;
    const unsigned short* kb = q2 + (size_t)(48 + bh) * NP * HD;
    const unsigned short* vtb = T + (size_t)(96 + bh) * HD * NP;

    #pragma unroll
    for (int hh = 0; hh < 2; ++hh)
        #pragma unroll
        for (int c = 0; c < 2; ++c)
            gld16(qb + (size_t)(w * 32 + c * 16 + lr) * HD + hh * 32 + lc,
                  &Qs[hh][w * 32 + c * 16][0]);

    f32x4 oacc[2][4] = {};
    float racc[2][4] = {};
    const int mlo = max(0, 2 * nt2 - 3), mhi = min(15, 2 * nt2 + 4);
    const unsigned int sel = (col & 1) ? 0x07060302u : 0x05040100u;

    for (int mt = mlo; mt <= mhi; ++mt) {
        const int m0 = mt * 64;
        __syncthreads();                   // prior iter's Ks/VT/Ss2 consumers done
        #pragma unroll
        for (int hh = 0; hh < 2; ++hh) {
            gld16(kb + (size_t)(m0 + w * 16 + lr) * HD + hh * 32 + lc, &Ks[hh][w * 16][0]);
            gld16(vtb + (size_t)(w * 16 + lr) * NP + m0 + hh * 32 + lc, &VT[hh][w * 16][0]);
        }
        float mreg[2][4][4];               // mask loads overlap the staging DMA
        #pragma unroll
        for (int rg = 0; rg < 2; ++rg)
            #pragma unroll
            for (int mtt = 0; mtt < 4; ++mtt)
                #pragma unroll
                for (int r = 0; r < 4; ++r)
                    mreg[rg][mtt][r] = mask[(size_t)(n0 + (w * 2 + rg) * 16 + quad * 4 + r) * NP
                                            + m0 + mtt * 16 + col];
        __syncthreads();

        f32x4 s[2][4] = {};
        #pragma unroll
        for (int ks = 0; ks < 2; ++ks) {
            bf16x8 bk[4];
            #pragma unroll
            for (int mtt = 0; mtt < 4; ++mtt) bk[mtt] = *(const bf16x8*)&Ks[ks][mtt * 16 + col][quad * 8];
            #pragma unroll
            for (int rg = 0; rg < 2; ++rg) {
                bf16x8 aq = *(const bf16x8*)&Qs[ks][(w * 2 + rg) * 16 + col][quad * 8];
                #pragma unroll
                for (int mtt = 0; mtt < 4; ++mtt) s[rg][mtt] = MFMA(aq, bk[mtt], s[rg][mtt]);
            }
        }
        #pragma unroll
        for (int rg = 0; rg < 2; ++rg) {
            const int npr = (w * 2 + rg) * 8 + quad * 2;
            #pragma unroll
            for (int mtt = 0; mtt < 4; ++mtt) {
                float v0 = s[rg][mtt][0] * mreg[rg][mtt][0];
                float v1 = s[rg][mtt][1] * mreg[rg][mtt][1];
                float v2 = s[rg][mtt][2] * mreg[rg][mtt][2];
                float v3 = s[rg][mtt][3] * mreg[rg][mtt][3];
                racc[rg][0] += v0; racc[rg][1] += v1;
                racc[rg][2] += v2; racc[rg][3] += v3;
                Ss2[npr][mtt * 16 + col]     = pk2(v0, v1);
                Ss2[npr + 1][mtt * 16 + col] = pk2(v2, v3);
            }
        }
        __syncthreads();
        #pragma unroll
        for (int ks = 0; ks < 2; ++ks) {
            bf16x8 bv[4];
            #pragma unroll
            for (int dt = 0; dt < 4; ++dt) bv[dt] = *(const bf16x8*)&VT[ks][dt * 16 + col][quad * 8];
            #pragma unroll
            for (int rg = 0; rg < 2; ++rg) {
                const unsigned int* rp = &Ss2[(w * 2 + rg) * 8 + (col >> 1)][ks * 32 + quad * 8];
                uint4 U  = *(const uint4*)rp;
                uint4 U2 = *(const uint4*)(rp + 4);
                uint4 fr;
                fr.x = __builtin_amdgcn_perm(U.y,  U.x,  sel);
                fr.y = __builtin_amdgcn_perm(U.w,  U.z,  sel);
                fr.z = __builtin_amdgcn_perm(U2.y, U2.x, sel);
                fr.w = __builtin_amdgcn_perm(U2.w, U2.z, sel);
                bf16x8 as = __builtin_bit_cast(bf16x8, fr);
                #pragma unroll
                for (int dt = 0; dt < 4; ++dt) oacc[rg][dt] = MFMA(as, bv[dt], oacc[rg][dt]);
            }
        }
    }

    #pragma unroll
    for (int rg = 0; rg < 2; ++rg)
        #pragma unroll
        for (int r = 0; r < 4; ++r) {
            float v = racc[rg][r];
            v += __shfl_xor(v, 1); v += __shfl_xor(v, 2);
            v += __shfl_xor(v, 4); v += __shfl_xor(v, 8);
            if (col == 0) rowz[(w * 2 + rg) * 16 + quad * 4 + r] = v;
        }
    __syncthreads();
    #pragma unroll
    for (int rg = 0; rg < 2; ++rg)
        #pragma unroll
        for (int r = 0; r < 4; ++r) {
            const int nl = (w * 2 + rg) * 16 + quad * 4 + r;
            const float z = 1.f / (rowz[nl] + EPS);
            #pragma unroll
            for (int dt = 0; dt < 4; ++dt)
                attnb[(size_t)(b * NP + n0 + nl) * DIM + h * HD + dt * 16 + col] =
                    f2b(oacc[rg][dt][r] * z);
        }
}

// --------------------------------------------------------------------------
// gemm2: out = attnb @ WoutT^T + b_out (fp32). 128m x 64n tiles, XCD-swizzled
// 1D grid (32 m-strips x 12 n-strips = 384 blocks).
// --------------------------------------------------------------------------
__global__ __launch_bounds__(256) void k_gemm2(const unsigned short* __restrict__ A,
                                               const unsigned short* __restrict__ Bt,
                                               const float* __restrict__ bias,
                                               float* __restrict__ C) {
    __shared__ unsigned short As[128][32];
    __shared__ unsigned short Bs[64][32];
    const int tid = threadIdx.x, w = tid >> 6, l = tid & 63;
    const int bid = blockIdx.x;                 // 384 blocks
    const int mstrip = (bid & 7) * 4 + ((bid >> 3) & 3);   // [0,32)
    const int nstrip = bid >> 5;                           // [0,12)
    const int m0 = mstrip * 128, n0 = nstrip * 64;
    const int wm = (w >> 1) * 64, wn = (w & 1) * 32;
    const int quad = l >> 4, col = l & 15;
    const int lr = l >> 2, lc = (l & 3) * 8;

    f32x4 acc[4][2] = {};
    for (int k0 = 0; k0 < DIM; k0 += 32) {
        gld16(A + (size_t)(m0 + w * 32 + lr) * DIM + k0 + lc, &As[w * 32][0]);
        gld16(A + (size_t)(m0 + w * 32 + 16 + lr) * DIM + k0 + lc, &As[w * 32 + 16][0]);
        gld16(Bt + (size_t)(n0 + w * 16 + lr) * DIM + k0 + lc, &Bs[w * 16][0]);
        __syncthreads();
        bf16x8 a[4], b[2];
        #pragma unroll
        for (int i = 0; i < 4; ++i) a[i] = *(const bf16x8*)&As[wm + i * 16 + col][quad * 8];
        #pragma unroll
        for (int j = 0; j < 2; ++j) b[j] = *(const bf16x8*)&Bs[wn + j * 16 + col][quad * 8];
        #pragma unroll
        for (int i = 0; i < 4; ++i)
            #pragma unroll
            for (int j = 0; j < 2; ++j)
                acc[i][j] = MFMA(a[i], b[j], acc[i][j]);
        __syncthreads();
    }
    #pragma unroll
    for (int i = 0; i < 4; ++i)
        #pragma unroll
        for (int j = 0; j < 2; ++j) {
            const int n = n0 + wn + j * 16 + col;
            #pragma unroll
            for (int r = 0; r < 4; ++r) {
                const int m = m0 + wm + i * 16 + quad * 4 + r;
                C[(size_t)m * DIM + n] = acc[i][j][r] + bias[n];
            }
        }
}

// --------------------------------------------------------------------------
extern "C" void kernel_launch(void* const* d_in, const int* in_sizes, int n_in,
                              void* d_out, int out_size, void* d_ws, size_t ws_size,
                              hipStream_t stream) {
    (void)in_sizes; (void)n_in; (void)out_size; (void)ws_size;
    const float* x     = (const float*)d_in[0];
    const float* W_qkv = (const float*)d_in[1];
    const float* W_out = (const float*)d_in[2];
    const float* b_out = (const float*)d_in[3];
    const float* mask  = (const float*)d_in[4];
    float* out = (float*)d_out;

    unsigned short* p = (unsigned short*)d_ws;
    unsigned short* xb    = p; p += (size_t)4096 * DIM;
    unsigned short* WqkvT = p; p += (size_t)TQ * DIM;
    unsigned short* WoutT = p; p += (size_t)DIM * DIM;
    unsigned short* M2    = p; p += (size_t)NP * NP;
    unsigned short* T     = p; p += (size_t)3 * 48 * HD * NP;
    unsigned short* q2    = p; p += (size_t)2 * 48 * NP * HD;
    unsigned short* attnb = p; p += (size_t)4096 * DIM;

    k_prep<<<dim3(2368), 256, 0, stream>>>(x, W_qkv, W_out, mask, xb, WqkvT, WoutT, M2);
    k_gemm1<<<dim3(576), 512, 0, stream>>>(xb, WqkvT, T);
    k_graphmix<<<dim3(NP / 64, 48), 256, 0, stream>>>(M2, T, q2);
    k_attn<<<dim3(NP / 128, 48), 256, 0, stream>>>(q2, T, mask, attnb);
    k_gemm2<<<dim3(384), 256, 0, stream>>>(attnb, WoutT, b_out, out);
}

// Round 7
// 163.037 us; speedup vs baseline: 1.0805x; 1.0026x over previous
//
#include <hip/hip_runtime.h>

#define NP   1024
#define DIM  768
#define NH   12
#define HD   64
#define TQ   2304
#define EPS  1e-6f

typedef __attribute__((ext_vector_type(8))) short bf16x8;
typedef __attribute__((ext_vector_type(4))) float f32x4;

#define MFMA(a, b, c) __builtin_amdgcn_mfma_f32_16x16x32_bf16((a), (b), (c), 0, 0, 0)

__device__ __forceinline__ unsigned short f2b(float x) {       // fp32 -> bf16 RNE
    unsigned int u = __builtin_bit_cast(unsigned int, x);
    u = (u + 0x7fffu + ((u >> 16) & 1u)) >> 16;
    return (unsigned short)u;
}
__device__ __forceinline__ float b2f(unsigned short h) {
    unsigned int u = ((unsigned int)h) << 16;
    return __builtin_bit_cast(float, u);
}
#if __has_builtin(__builtin_amdgcn_cvt_pk_bf16_f32)
typedef __attribute__((ext_vector_type(2))) __bf16 bf16x2t;
__device__ __forceinline__ unsigned int pk2(float lo, float hi) {
    bf16x2t v = __builtin_amdgcn_cvt_pk_bf16_f32(lo, hi);
    return __builtin_bit_cast(unsigned int, v);
}
#else
__device__ __forceinline__ unsigned int pk2(float lo, float hi) {
    return (unsigned int)f2b(lo) | ((unsigned int)f2b(hi) << 16);
}
#endif
__device__ __forceinline__ void gld16(const void* g, void* l) { // 16B global -> LDS
    __builtin_amdgcn_global_load_lds((const __attribute__((address_space(1))) unsigned int*)g,
                                     (__attribute__((address_space(3))) unsigned int*)l,
                                     16, 0, 0);
}

// --------------------------------------------------------------------------
// fused prep: convert x -> bf16 ; transpose W_qkv, W_out -> bf16 ;
// M2 = 0.1*mask^T + I -> bf16 (graphmix residual folded into the operator)
// --------------------------------------------------------------------------
__global__ __launch_bounds__(256) void k_prep(const float* __restrict__ x,
                                              const float* __restrict__ W_qkv,
                                              const float* __restrict__ W_out,
                                              const float* __restrict__ mask,
                                              unsigned short* __restrict__ xb,
                                              unsigned short* __restrict__ WqkvT,
                                              unsigned short* __restrict__ WoutT,
                                              unsigned short* __restrict__ M2) {
    __shared__ float buf[64][65];
    const int bx = blockIdx.x, t = threadIdx.x;
    if (bx < 1536) {                       // convert x (4096*768 elems, 8/thread)
        const int i = bx * 256 + t;
        const float4* p = (const float4*)x + (size_t)i * 2;
        float4 a = p[0], b = p[1];
        alignas(16) unsigned short o[8] = {f2b(a.x), f2b(a.y), f2b(a.z), f2b(a.w),
                                           f2b(b.x), f2b(b.y), f2b(b.z), f2b(b.w)};
        *(uint4*)(xb + (size_t)i * 8) = *(const uint4*)o;
        return;
    }
    const float* in; unsigned short* outp; int R, C, ct, rt; bool isMask = false;
    if (bx < 1968)      { int q = bx - 1536; in = W_qkv; outp = WqkvT; R = 768;  C = 2304; ct = q % 36; rt = q / 36; }
    else if (bx < 2112) { int q = bx - 1968; in = W_out; outp = WoutT; R = 768;  C = 768;  ct = q % 12; rt = q / 12; }
    else                { int q = bx - 2112; in = mask;  outp = M2;    R = 1024; C = 1024; ct = q % 16; rt = q / 16; isMask = true; }
    const int r0 = rt * 64, c0 = ct * 64;
    const int rr = t >> 4, cc = (t & 15) * 4;
    #pragma unroll
    for (int p = 0; p < 4; ++p) {
        float4 v = *(const float4*)(in + (size_t)(r0 + p * 16 + rr) * C + c0 + cc);
        buf[p * 16 + rr][cc + 0] = v.x; buf[p * 16 + rr][cc + 1] = v.y;
        buf[p * 16 + rr][cc + 2] = v.z; buf[p * 16 + rr][cc + 3] = v.w;
    }
    __syncthreads();
    const int oc = t >> 2, orr = (t & 3) * 16;
    alignas(16) unsigned short tmp[16];
    if (isMask) {
        #pragma unroll
        for (int j = 0; j < 16; ++j) {
            float v = 0.1f * buf[orr + j][oc] + ((c0 + oc) == (r0 + orr + j) ? 1.f : 0.f);
            tmp[j] = f2b(v);
        }
    } else {
        #pragma unroll
        for (int j = 0; j < 16; ++j) tmp[j] = f2b(buf[orr + j][oc]);
    }
    unsigned short* dst = outp + (size_t)(c0 + oc) * R + r0 + orr;
    *(uint4*)dst = *(const uint4*)tmp;
    *(uint4*)(dst + 8) = *(const uint4*)(tmp + 8);
}

// --------------------------------------------------------------------------
// gemm1: qkv = xb @ WqkvT^T, 512 threads (8 waves), 128x128 tile, BK=32.
// XCD-swizzled 1D grid. Epilogue: direct packed stores to transposed
// T[slot*48+b*12+h][d][np], relu+eps fused on q,k slots.
// --------------------------------------------------------------------------
__global__ __launch_bounds__(512) void k_gemm1(const unsigned short* __restrict__ A,
                                               const unsigned short* __restrict__ Bt,
                                               unsigned short* __restrict__ T) {
    __shared__ unsigned short As[128][32];
    __shared__ unsigned short Bs[128][32];
    const int tid = threadIdx.x, w = tid >> 6, l = tid & 63;
    const int bid = blockIdx.x;                 // 576 blocks
    const int mstrip = (bid & 7) * 4 + ((bid >> 3) & 3);   // [0,32)
    const int nstrip = bid >> 5;                           // [0,18)
    const int m0 = mstrip * 128, n0 = nstrip * 128;
    const int wm = (w & 3) * 32, wn = (w >> 2) * 64;
    const int quad = l >> 4, col = l & 15;
    const int lr = l >> 2, lc = (l & 3) * 8;

    f32x4 acc[2][4] = {};
    for (int k0 = 0; k0 < DIM; k0 += 32) {
        gld16(A + (size_t)(m0 + w * 16 + lr) * DIM + k0 + lc, &As[w * 16][0]);
        gld16(Bt + (size_t)(n0 + w * 16 + lr) * DIM + k0 + lc, &Bs[w * 16][0]);
        __syncthreads();
        bf16x8 a[2], b[4];
        #pragma unroll
        for (int i = 0; i < 2; ++i) a[i] = *(const bf16x8*)&As[wm + i * 16 + col][quad * 8];
        #pragma unroll
        for (int j = 0; j < 4; ++j) b[j] = *(const bf16x8*)&Bs[wn + j * 16 + col][quad * 8];
        #pragma unroll
        for (int i = 0; i < 2; ++i)
            #pragma unroll
            for (int j = 0; j < 4; ++j)
                acc[i][j] = MFMA(a[i], b[j], acc[i][j]);
        __syncthreads();
    }

    const int cgb = n0 + wn;                    // multiple of 64 -> fixed slot,h
    const int slot = cgb / DIM;
    const int h = (cgb % DIM) >> 6;
    const bool act = (slot < 2);
    const int sh = slot * 48 + (m0 >> 10) * NH + h;
    const int npb = (m0 & 1023) + wm + quad * 4;
    #pragma unroll
    for (int j = 0; j < 4; ++j) {
        unsigned short* dcol = T + ((size_t)(sh * HD + j * 16 + col)) * NP + npb;
        #pragma unroll
        for (int i = 0; i < 2; ++i) {
            float v0 = acc[i][j][0], v1 = acc[i][j][1], v2 = acc[i][j][2], v3 = acc[i][j][3];
            if (act) {
                v0 = fmaxf(v0, 0.f) + EPS; v1 = fmaxf(v1, 0.f) + EPS;
                v2 = fmaxf(v2, 0.f) + EPS; v3 = fmaxf(v3, 0.f) + EPS;
            }
            uint2 o; o.x = pk2(v0, v1); o.y = pk2(v2, v3);
            *(uint2*)(dcol + i * 16) = o;
        }
    }
}

// --------------------------------------------------------------------------
// graphmix: pure banded GEMM  q2[m][d] = sum_n M2[m][n] * f(n,d)
// (M2 = 0.1*mask^T + I). D rows = d -> packed 8B stores to q2[m][d].
// --------------------------------------------------------------------------
__global__ __launch_bounds__(256) void k_graphmix(const unsigned short* __restrict__ M2,
                                                  const unsigned short* __restrict__ T,
                                                  unsigned short* __restrict__ q2) {
    const int bh = blockIdx.y, mt = blockIdx.x;
    const int m0 = mt * 64;
    __shared__ unsigned short M2s[2][64][32], Fq[2][64][32], Fk[2][64][32];
    const int tid = threadIdx.x, w = tid >> 6, l = tid & 63;
    const int quad = l >> 4, col = l & 15;
    const int lr = l >> 2, lc = (l & 3) * 8;
    const unsigned short* Tq = T + (size_t)bh * HD * NP;
    const unsigned short* Tk = T + (size_t)(48 + bh) * HD * NP;

    f32x4 accq[4] = {}, acck[4] = {};
    const int c0 = max(0, mt - 3), c1 = min(15, mt + 3);
    for (int c = c0; c <= c1; ++c) {
        const int nc = c * 64;
        __syncthreads();
        #pragma unroll
        for (int hh = 0; hh < 2; ++hh) {
            gld16(M2 + (size_t)(m0 + w * 16 + lr) * NP + nc + hh * 32 + lc, &M2s[hh][w * 16][0]);
            gld16(Tq + (size_t)(w * 16 + lr) * NP + nc + hh * 32 + lc, &Fq[hh][w * 16][0]);
            gld16(Tk + (size_t)(w * 16 + lr) * NP + nc + hh * 32 + lc, &Fk[hh][w * 16][0]);
        }
        __syncthreads();
        #pragma unroll
        for (int ks = 0; ks < 2; ++ks) {
            bf16x8 bm = *(const bf16x8*)&M2s[ks][w * 16 + col][quad * 8];   // B: cols=m
            #pragma unroll
            for (int dt = 0; dt < 4; ++dt) {
                bf16x8 aq = *(const bf16x8*)&Fq[ks][dt * 16 + col][quad * 8]; // A: rows=d
                bf16x8 ak = *(const bf16x8*)&Fk[ks][dt * 16 + col][quad * 8];
                accq[dt] = MFMA(aq, bm, accq[dt]);
                acck[dt] = MFMA(ak, bm, acck[dt]);
            }
        }
    }
    unsigned short* q2q = q2 + ((size_t)bh * NP + m0 + w * 16 + col) * HD;
    unsigned short* q2k = q2 + ((size_t)(48 + bh) * NP + m0 + w * 16 + col) * HD;
    #pragma unroll
    for (int dt = 0; dt < 4; ++dt) {
        const int d0 = dt * 16 + quad * 4;
        uint2 oq; oq.x = pk2(accq[dt][0], accq[dt][1]); oq.y = pk2(accq[dt][2], accq[dt][3]);
        uint2 ok; ok.x = pk2(acck[dt][0], acck[dt][1]); ok.y = pk2(acck[dt][2], acck[dt][3]);
        *(uint2*)(q2q + d0) = oq;
        *(uint2*)(q2k + d0) = ok;
    }
}

// --------------------------------------------------------------------------
// attention: 64-row Q tiles (grid 16x48 = 768 blocks = 3.0 even rounds/CU,
// ~19% fewer band FLOPs than 128-row union); band m-tiles [nt-3, nt+3];
// mask register loads overlap staging DMA; S round-trip via packed n-pair
// dwords + v_perm rebuild. LDS ~33 KB -> 4 blocks/CU limit.
// --------------------------------------------------------------------------
__global__ __launch_bounds__(256) void k_attn(const unsigned short* __restrict__ q2,
                                              const unsigned short* __restrict__ T,
                                              const float* __restrict__ mask,
                                              unsigned short* __restrict__ attnb) {
    const int bh = blockIdx.y, b = bh / NH, h = bh % NH;
    const int nt = blockIdx.x, n0 = nt * 64;
    __shared__ unsigned short Qs[2][64][32];
    __shared__ unsigned short Ks[2][64][32];
    __shared__ unsigned short VT[2][64][32];
    __shared__ unsigned int Ss2[32][68];          // [n>>1][m] pitch 68 dwords
    __shared__ float rowz[64];
    const int tid = threadIdx.x, w = tid >> 6, l = tid & 63;
    const int quad = l >> 4, col = l & 15;
    const int lr = l >> 2, lc = (l & 3) * 8;

    const unsigned short* qb = q2 + ((size_t)bh * NP + n0) * HD;
    const unsigned short* kb = q2 + (size_t)(48 + bh) * NP * HD;
    const unsigned short* vtb = T + (size_t)(96 + bh) * HD * NP;

    #pragma unroll
    for (int hh = 0; hh < 2; ++hh)
        gld16(qb + (size_t)(w * 16 + lr) * HD + hh * 32 + lc, &Qs[hh][w * 16][0]);

    f32x4 oacc[4] = {};
    float racc[4] = {};
    const int mlo = max(0, nt - 3), mhi = min(15, nt + 3);
    const unsigned int sel = (col & 1) ? 0x07060302u : 0x05040100u;

    for (int mt = mlo; mt <= mhi; ++mt) {
        const int m0 = mt * 64;
        __syncthreads();                   // prior iter's Ks/VT/Ss2 consumers done
        #pragma unroll
        for (int hh = 0; hh < 2; ++hh) {
            gld16(kb + (size_t)(m0 + w * 16 + lr) * HD + hh * 32 + lc, &Ks[hh][w * 16][0]);
            gld16(vtb + (size_t)(w * 16 + lr) * NP + m0 + hh * 32 + lc, &VT[hh][w * 16][0]);
        }
        float mreg[4][4];                  // mask loads overlap the staging DMA
        #pragma unroll
        for (int mtt = 0; mtt < 4; ++mtt)
            #pragma unroll
            for (int r = 0; r < 4; ++r)
                mreg[mtt][r] = mask[(size_t)(n0 + w * 16 + quad * 4 + r) * NP
                                    + m0 + mtt * 16 + col];
        __syncthreads();

        f32x4 s[4] = {};
        #pragma unroll
        for (int ks = 0; ks < 2; ++ks) {
            bf16x8 aq = *(const bf16x8*)&Qs[ks][w * 16 + col][quad * 8];
            #pragma unroll
            for (int mtt = 0; mtt < 4; ++mtt) {
                bf16x8 bk = *(const bf16x8*)&Ks[ks][mtt * 16 + col][quad * 8];
                s[mtt] = MFMA(aq, bk, s[mtt]);
            }
        }
        {
            const int npr = w * 8 + quad * 2;
            #pragma unroll
            for (int mtt = 0; mtt < 4; ++mtt) {
                float v0 = s[mtt][0] * mreg[mtt][0];
                float v1 = s[mtt][1] * mreg[mtt][1];
                float v2 = s[mtt][2] * mreg[mtt][2];
                float v3 = s[mtt][3] * mreg[mtt][3];
                racc[0] += v0; racc[1] += v1; racc[2] += v2; racc[3] += v3;
                Ss2[npr][mtt * 16 + col]     = pk2(v0, v1);
                Ss2[npr + 1][mtt * 16 + col] = pk2(v2, v3);
            }
        }
        __syncthreads();
        #pragma unroll
        for (int ks = 0; ks < 2; ++ks) {
            const unsigned int* rp = &Ss2[w * 8 + (col >> 1)][ks * 32 + quad * 8];
            uint4 U  = *(const uint4*)rp;
            uint4 U2 = *(const uint4*)(rp + 4);
            uint4 fr;
            fr.x = __builtin_amdgcn_perm(U.y,  U.x,  sel);
            fr.y = __builtin_amdgcn_perm(U.w,  U.z,  sel);
            fr.z = __builtin_amdgcn_perm(U2.y, U2.x, sel);
            fr.w = __builtin_amdgcn_perm(U2.w, U2.z, sel);
            bf16x8 as = __builtin_bit_cast(bf16x8, fr);
            #pragma unroll
            for (int dt = 0; dt < 4; ++dt) {
                bf16x8 bv = *(const bf16x8*)&VT[ks][dt * 16 + col][quad * 8];
                oacc[dt] = MFMA(as, bv, oacc[dt]);
            }
        }
    }

    #pragma unroll
    for (int r = 0; r < 4; ++r) {
        float v = racc[r];
        v += __shfl_xor(v, 1); v += __shfl_xor(v, 2);
        v += __shfl_xor(v, 4); v += __shfl_xor(v, 8);
        if (col == 0) rowz[w * 16 + quad * 4 + r] = v;
    }
    __syncthreads();
    #pragma unroll
    for (int r = 0; r < 4; ++r) {
        const int nl = w * 16 + quad * 4 + r;
        const float z = 1.f / (rowz[nl] + EPS);
        #pragma unroll
        for (int dt = 0; dt < 4; ++dt)
            attnb[(size_t)(b * NP + n0 + nl) * DIM + h * HD + dt * 16 + col] =
                f2b(oacc[dt][r] * z);
    }
}

// --------------------------------------------------------------------------
// gemm2: out = attnb @ WoutT^T + b_out (fp32). 128m x 64n tiles, XCD-swizzled
// 1D grid (32 m-strips x 12 n-strips = 384 blocks).
// --------------------------------------------------------------------------
__global__ __launch_bounds__(256) void k_gemm2(const unsigned short* __restrict__ A,
                                               const unsigned short* __restrict__ Bt,
                                               const float* __restrict__ bias,
                                               float* __restrict__ C) {
    __shared__ unsigned short As[128][32];
    __shared__ unsigned short Bs[64][32];
    const int tid = threadIdx.x, w = tid >> 6, l = tid & 63;
    const int bid = blockIdx.x;                 // 384 blocks
    const int mstrip = (bid & 7) * 4 + ((bid >> 3) & 3);   // [0,32)
    const int nstrip = bid >> 5;                           // [0,12)
    const int m0 = mstrip * 128, n0 = nstrip * 64;
    const int wm = (w >> 1) * 64, wn = (w & 1) * 32;
    const int quad = l >> 4, col = l & 15;
    const int lr = l >> 2, lc = (l & 3) * 8;

    f32x4 acc[4][2] = {};
    for (int k0 = 0; k0 < DIM; k0 += 32) {
        gld16(A + (size_t)(m0 + w * 32 + lr) * DIM + k0 + lc, &As[w * 32][0]);
        gld16(A + (size_t)(m0 + w * 32 + 16 + lr) * DIM + k0 + lc, &As[w * 32 + 16][0]);
        gld16(Bt + (size_t)(n0 + w * 16 + lr) * DIM + k0 + lc, &Bs[w * 16][0]);
        __syncthreads();
        bf16x8 a[4], b[2];
        #pragma unroll
        for (int i = 0; i < 4; ++i) a[i] = *(const bf16x8*)&As[wm + i * 16 + col][quad * 8];
        #pragma unroll
        for (int j = 0; j < 2; ++j) b[j] = *(const bf16x8*)&Bs[wn + j * 16 + col][quad * 8];
        #pragma unroll
        for (int i = 0; i < 4; ++i)
            #pragma unroll
            for (int j = 0; j < 2; ++j)
                acc[i][j] = MFMA(a[i], b[j], acc[i][j]);
        __syncthreads();
    }
    #pragma unroll
    for (int i = 0; i < 4; ++i)
        #pragma unroll
        for (int j = 0; j < 2; ++j) {
            const int n = n0 + wn + j * 16 + col;
            #pragma unroll
            for (int r = 0; r < 4; ++r) {
                const int m = m0 + wm + i * 16 + quad * 4 + r;
                C[(size_t)m * DIM + n] = acc[i][j][r] + bias[n];
            }
        }
}

// --------------------------------------------------------------------------
extern "C" void kernel_launch(void* const* d_in, const int* in_sizes, int n_in,
                              void* d_out, int out_size, void* d_ws, size_t ws_size,
                              hipStream_t stream) {
    (void)in_sizes; (void)n_in; (void)out_size; (void)ws_size;
    const float* x     = (const float*)d_in[0];
    const float* W_qkv = (const float*)d_in[1];
    const float* W_out = (const float*)d_in[2];
    const float* b_out = (const float*)d_in[3];
    const float* mask  = (const float*)d_in[4];
    float* out = (float*)d_out;

    unsigned short* p = (unsigned short*)d_ws;
    unsigned short* xb    = p; p += (size_t)4096 * DIM;
    unsigned short* WqkvT = p; p += (size_t)TQ * DIM;
    unsigned short* WoutT = p; p += (size_t)DIM * DIM;
    unsigned short* M2    = p; p += (size_t)NP * NP;
    unsigned short* T     = p; p += (size_t)3 * 48 * HD * NP;
    unsigned short* q2    = p; p += (size_t)2 * 48 * NP * HD;
    unsigned short* attnb = p; p += (size_t)4096 * DIM;

    k_prep<<<dim3(2368), 256, 0, stream>>>(x, W_qkv, W_out, mask, xb, WqkvT, WoutT, M2);
    k_gemm1<<<dim3(576), 512, 0, stream>>>(xb, WqkvT, T);
    k_graphmix<<<dim3(NP / 64, 48), 256, 0, stream>>>(M2, T, q2);
    k_attn<<<dim3(NP / 64, 48), 256, 0, stream>>>(q2, T, mask, attnb);
    k_gemm2<<<dim3(384), 256, 0, stream>>>(attnb, WoutT, b_out, out);
}

// Round 8
// 156.811 us; speedup vs baseline: 1.1234x; 1.0397x over previous
//
#include <hip/hip_runtime.h>

#define NP   1024
#define DIM  768
#define NH   12
#define HD   64
#define TQ   2304
#define EPS  1e-6f

typedef __attribute__((ext_vector_type(8))) short bf16x8;
typedef __attribute__((ext_vector_type(4))) float f32x4;

#define MFMA(a, b, c) __builtin_amdgcn_mfma_f32_16x16x32_bf16((a), (b), (c), 0, 0, 0)

__device__ __forceinline__ unsigned short f2b(float x) {       // fp32 -> bf16 RNE
    unsigned int u = __builtin_bit_cast(unsigned int, x);
    u = (u + 0x7fffu + ((u >> 16) & 1u)) >> 16;
    return (unsigned short)u;
}
__device__ __forceinline__ float b2f(unsigned short h) {
    unsigned int u = ((unsigned int)h) << 16;
    return __builtin_bit_cast(float, u);
}
#if __has_builtin(__builtin_amdgcn_cvt_pk_bf16_f32)
typedef __attribute__((ext_vector_type(2))) __bf16 bf16x2t;
__device__ __forceinline__ unsigned int pk2(float lo, float hi) {
    bf16x2t v = __builtin_amdgcn_cvt_pk_bf16_f32(lo, hi);
    return __builtin_bit_cast(unsigned int, v);
}
#else
__device__ __forceinline__ unsigned int pk2(float lo, float hi) {
    return (unsigned int)f2b(lo) | ((unsigned int)f2b(hi) << 16);
}
#endif
__device__ __forceinline__ void gld16(const void* g, void* l) { // 16B global -> LDS
    __builtin_amdgcn_global_load_lds((const __attribute__((address_space(1))) unsigned int*)g,
                                     (__attribute__((address_space(3))) unsigned int*)l,
                                     16, 0, 0);
}

// --------------------------------------------------------------------------
// prep (x-convert moved into gemm1): transpose W_qkv, W_out -> bf16 ;
// M2 = 0.1*mask^T + I -> bf16
// --------------------------------------------------------------------------
__global__ __launch_bounds__(256) void k_prep(const float* __restrict__ W_qkv,
                                              const float* __restrict__ W_out,
                                              const float* __restrict__ mask,
                                              unsigned short* __restrict__ WqkvT,
                                              unsigned short* __restrict__ WoutT,
                                              unsigned short* __restrict__ M2) {
    __shared__ float buf[64][65];
    const int bx = blockIdx.x, t = threadIdx.x;
    const float* in; unsigned short* outp; int R, C, ct, rt; bool isMask = false;
    if (bx < 432)      { int q = bx;       in = W_qkv; outp = WqkvT; R = 768;  C = 2304; ct = q % 36; rt = q / 36; }
    else if (bx < 576) { int q = bx - 432; in = W_out; outp = WoutT; R = 768;  C = 768;  ct = q % 12; rt = q / 12; }
    else               { int q = bx - 576; in = mask;  outp = M2;    R = 1024; C = 1024; ct = q % 16; rt = q / 16; isMask = true; }
    const int r0 = rt * 64, c0 = ct * 64;
    const int rr = t >> 4, cc = (t & 15) * 4;
    #pragma unroll
    for (int p = 0; p < 4; ++p) {
        float4 v = *(const float4*)(in + (size_t)(r0 + p * 16 + rr) * C + c0 + cc);
        buf[p * 16 + rr][cc + 0] = v.x; buf[p * 16 + rr][cc + 1] = v.y;
        buf[p * 16 + rr][cc + 2] = v.z; buf[p * 16 + rr][cc + 3] = v.w;
    }
    __syncthreads();
    const int oc = t >> 2, orr = (t & 3) * 16;
    alignas(16) unsigned short tmp[16];
    if (isMask) {
        #pragma unroll
        for (int j = 0; j < 16; ++j) {
            float v = 0.1f * buf[orr + j][oc] + ((c0 + oc) == (r0 + orr + j) ? 1.f : 0.f);
            tmp[j] = f2b(v);
        }
    } else {
        #pragma unroll
        for (int j = 0; j < 16; ++j) tmp[j] = f2b(buf[orr + j][oc]);
    }
    unsigned short* dst = outp + (size_t)(c0 + oc) * R + r0 + orr;
    *(uint4*)dst = *(const uint4*)tmp;
    *(uint4*)(dst + 8) = *(const uint4*)(tmp + 8);
}

// --------------------------------------------------------------------------
// gemm1: qkv = x @ WqkvT^T. 512 thr, 128x128 tile, BK=64 (12 iters, 16
// MFMA/wave/iter -> half the barrier drains of BK=32). A staged from fp32 x
// with in-register cvt_pk (kills the separate convert pass); B via gld16.
// Epilogue: direct packed stores to T[slot*48+b*12+h][d][np], relu+eps q,k.
// --------------------------------------------------------------------------
__global__ __launch_bounds__(512) void k_gemm1(const float* __restrict__ X,
                                               const unsigned short* __restrict__ Bt,
                                               unsigned short* __restrict__ T) {
    __shared__ unsigned short As[2][128][32];
    __shared__ unsigned short Bs[2][128][32];
    const int tid = threadIdx.x, w = tid >> 6, l = tid & 63;
    const int bid = blockIdx.x;                 // 576 blocks
    const int mstrip = (bid & 7) * 4 + ((bid >> 3) & 3);   // [0,32)
    const int nstrip = bid >> 5;                           // [0,18)
    const int m0 = mstrip * 128, n0 = nstrip * 128;
    const int wm = (w & 3) * 32, wn = (w >> 2) * 64;
    const int quad = l >> 4, col = l & 15;
    const int lr = l >> 2, lc = (l & 3) * 8;
    const int arow = tid >> 2, akc = (tid & 3) * 8;        // A-staging map

    f32x4 acc[2][4] = {};
    for (int k0 = 0; k0 < DIM; k0 += 64) {
        #pragma unroll
        for (int hh = 0; hh < 2; ++hh) {
            gld16(Bt + (size_t)(n0 + w * 16 + lr) * DIM + k0 + hh * 32 + lc, &Bs[hh][w * 16][0]);
            const float* xp = X + (size_t)(m0 + arow) * DIM + k0 + hh * 32 + akc;
            float4 xa = *(const float4*)xp;
            float4 xb = *(const float4*)(xp + 4);
            uint4 o;
            o.x = pk2(xa.x, xa.y); o.y = pk2(xa.z, xa.w);
            o.z = pk2(xb.x, xb.y); o.w = pk2(xb.z, xb.w);
            *(uint4*)&As[hh][arow][akc] = o;
        }
        __syncthreads();
        #pragma unroll
        for (int hh = 0; hh < 2; ++hh) {
            bf16x8 a[2], b[4];
            #pragma unroll
            for (int i = 0; i < 2; ++i) a[i] = *(const bf16x8*)&As[hh][wm + i * 16 + col][quad * 8];
            #pragma unroll
            for (int j = 0; j < 4; ++j) b[j] = *(const bf16x8*)&Bs[hh][wn + j * 16 + col][quad * 8];
            #pragma unroll
            for (int i = 0; i < 2; ++i)
                #pragma unroll
                for (int j = 0; j < 4; ++j)
                    acc[i][j] = MFMA(a[i], b[j], acc[i][j]);
        }
        __syncthreads();
    }

    const int cgb = n0 + wn;                    // multiple of 64 -> fixed slot,h
    const int slot = cgb / DIM;
    const int h = (cgb % DIM) >> 6;
    const bool act = (slot < 2);
    const int sh = slot * 48 + (m0 >> 10) * NH + h;
    const int npb = (m0 & 1023) + wm + quad * 4;
    #pragma unroll
    for (int j = 0; j < 4; ++j) {
        unsigned short* dcol = T + ((size_t)(sh * HD + j * 16 + col)) * NP + npb;
        #pragma unroll
        for (int i = 0; i < 2; ++i) {
            float v0 = acc[i][j][0], v1 = acc[i][j][1], v2 = acc[i][j][2], v3 = acc[i][j][3];
            if (act) {
                v0 = fmaxf(v0, 0.f) + EPS; v1 = fmaxf(v1, 0.f) + EPS;
                v2 = fmaxf(v2, 0.f) + EPS; v3 = fmaxf(v3, 0.f) + EPS;
            }
            uint2 o; o.x = pk2(v0, v1); o.y = pk2(v2, v3);
            *(uint2*)(dcol + i * 16) = o;
        }
    }
}

// --------------------------------------------------------------------------
// graphmix: q2[m][d] = sum_n M2[m][n] f(n,d). Band exact at 32-row
// granularity: n-rows [2mt-5, 2mt+6] = 384 n = 3 iters of K=128 (was 7x64).
// 32 MFMA/wave per barrier-pair. D rows = d -> packed 8B stores.
// --------------------------------------------------------------------------
__global__ __launch_bounds__(256) void k_graphmix(const unsigned short* __restrict__ M2,
                                                  const unsigned short* __restrict__ T,
                                                  unsigned short* __restrict__ q2) {
    const int bh = blockIdx.y, mt = blockIdx.x;
    const int m0 = mt * 64;
    __shared__ unsigned short M2s[4][64][32], Fq[4][64][32], Fk[4][64][32];
    const int tid = threadIdx.x, w = tid >> 6, l = tid & 63;
    const int quad = l >> 4, col = l & 15;
    const int lr = l >> 2, lc = (l & 3) * 8;
    const unsigned short* Tq = T + (size_t)bh * HD * NP;
    const unsigned short* Tk = T + (size_t)(48 + bh) * HD * NP;

    f32x4 accq[4] = {}, acck[4] = {};
    const int nr0 = min(max(2 * mt - 5, 0), 20) * 32;   // 12-row window start
    for (int it = 0; it < 3; ++it) {
        const int nc = nr0 + it * 128;
        __syncthreads();
        #pragma unroll
        for (int hh = 0; hh < 4; ++hh) {
            gld16(M2 + (size_t)(m0 + w * 16 + lr) * NP + nc + hh * 32 + lc, &M2s[hh][w * 16][0]);
            gld16(Tq + (size_t)(w * 16 + lr) * NP + nc + hh * 32 + lc, &Fq[hh][w * 16][0]);
            gld16(Tk + (size_t)(w * 16 + lr) * NP + nc + hh * 32 + lc, &Fk[hh][w * 16][0]);
        }
        __syncthreads();
        #pragma unroll
        for (int ks = 0; ks < 4; ++ks) {
            bf16x8 bm = *(const bf16x8*)&M2s[ks][w * 16 + col][quad * 8];   // B: cols=m
            #pragma unroll
            for (int dt = 0; dt < 4; ++dt) {
                bf16x8 aq = *(const bf16x8*)&Fq[ks][dt * 16 + col][quad * 8]; // A: rows=d
                bf16x8 ak = *(const bf16x8*)&Fk[ks][dt * 16 + col][quad * 8];
                accq[dt] = MFMA(aq, bm, accq[dt]);
                acck[dt] = MFMA(ak, bm, acck[dt]);
            }
        }
    }
    unsigned short* q2q = q2 + ((size_t)bh * NP + m0 + w * 16 + col) * HD;
    unsigned short* q2k = q2 + ((size_t)(48 + bh) * NP + m0 + w * 16 + col) * HD;
    #pragma unroll
    for (int dt = 0; dt < 4; ++dt) {
        const int d0 = dt * 16 + quad * 4;
        uint2 oq; oq.x = pk2(accq[dt][0], accq[dt][1]); oq.y = pk2(accq[dt][2], accq[dt][3]);
        uint2 ok; ok.x = pk2(acck[dt][0], acck[dt][1]); ok.y = pk2(acck[dt][2], acck[dt][3]);
        *(uint2*)(q2q + d0) = oq;
        *(uint2*)(q2k + d0) = ok;
    }
}

// --------------------------------------------------------------------------
// attention: 64-row Q tiles; EXACT 32-row-aligned m-band [2nt-5, 2nt+6] =
// 384 m = 6 iters of 64 (was 7); mask reg loads overlap staging DMA;
// S round-trip via packed n-pair dwords + v_perm rebuild.
// --------------------------------------------------------------------------
__global__ __launch_bounds__(256) void k_attn(const unsigned short* __restrict__ q2,
                                              const unsigned short* __restrict__ T,
                                              const float* __restrict__ mask,
                                              unsigned short* __restrict__ attnb) {
    const int bh = blockIdx.y, b = bh / NH, h = bh % NH;
    const int nt = blockIdx.x, n0 = nt * 64;
    __shared__ unsigned short Qs[2][64][32];
    __shared__ unsigned short Ks[2][64][32];
    __shared__ unsigned short VT[2][64][32];
    __shared__ unsigned int Ss2[32][68];          // [n>>1][m] pitch 68 dwords
    __shared__ float rowz[64];
    const int tid = threadIdx.x, w = tid >> 6, l = tid & 63;
    const int quad = l >> 4, col = l & 15;
    const int lr = l >> 2, lc = (l & 3) * 8;

    const unsigned short* qb = q2 + ((size_t)bh * NP + n0) * HD;
    const unsigned short* kb = q2 + (size_t)(48 + bh) * NP * HD;
    const unsigned short* vtb = T + (size_t)(96 + bh) * HD * NP;

    #pragma unroll
    for (int hh = 0; hh < 2; ++hh)
        gld16(qb + (size_t)(w * 16 + lr) * HD + hh * 32 + lc, &Qs[hh][w * 16][0]);

    f32x4 oacc[4] = {};
    float racc[4] = {};
    const int mr0 = min(max(2 * nt - 5, 0), 20) * 32;   // 12-row window start
    const unsigned int sel = (col & 1) ? 0x07060302u : 0x05040100u;

    for (int it = 0; it < 6; ++it) {
        const int m0 = mr0 + it * 64;
        __syncthreads();                   // prior iter's Ks/VT/Ss2 consumers done
        #pragma unroll
        for (int hh = 0; hh < 2; ++hh) {
            gld16(kb + (size_t)(m0 + w * 16 + lr) * HD + hh * 32 + lc, &Ks[hh][w * 16][0]);
            gld16(vtb + (size_t)(w * 16 + lr) * NP + m0 + hh * 32 + lc, &VT[hh][w * 16][0]);
        }
        float mreg[4][4];                  // mask loads overlap the staging DMA
        #pragma unroll
        for (int mtt = 0; mtt < 4; ++mtt)
            #pragma unroll
            for (int r = 0; r < 4; ++r)
                mreg[mtt][r] = mask[(size_t)(n0 + w * 16 + quad * 4 + r) * NP
                                    + m0 + mtt * 16 + col];
        __syncthreads();

        f32x4 s[4] = {};
        #pragma unroll
        for (int ks = 0; ks < 2; ++ks) {
            bf16x8 aq = *(const bf16x8*)&Qs[ks][w * 16 + col][quad * 8];
            #pragma unroll
            for (int mtt = 0; mtt < 4; ++mtt) {
                bf16x8 bk = *(const bf16x8*)&Ks[ks][mtt * 16 + col][quad * 8];
                s[mtt] = MFMA(aq, bk, s[mtt]);
            }
        }
        {
            const int npr = w * 8 + quad * 2;
            #pragma unroll
            for (int mtt = 0; mtt < 4; ++mtt) {
                float v0 = s[mtt][0] * mreg[mtt][0];
                float v1 = s[mtt][1] * mreg[mtt][1];
                float v2 = s[mtt][2] * mreg[mtt][2];
                float v3 = s[mtt][3] * mreg[mtt][3];
                racc[0] += v0; racc[1] += v1; racc[2] += v2; racc[3] += v3;
                Ss2[npr][mtt * 16 + col]     = pk2(v0, v1);
                Ss2[npr + 1][mtt * 16 + col] = pk2(v2, v3);
            }
        }
        __syncthreads();
        #pragma unroll
        for (int ks = 0; ks < 2; ++ks) {
            const unsigned int* rp = &Ss2[w * 8 + (col >> 1)][ks * 32 + quad * 8];
            uint4 U  = *(const uint4*)rp;
            uint4 U2 = *(const uint4*)(rp + 4);
            uint4 fr;
            fr.x = __builtin_amdgcn_perm(U.y,  U.x,  sel);
            fr.y = __builtin_amdgcn_perm(U.w,  U.z,  sel);
            fr.z = __builtin_amdgcn_perm(U2.y, U2.x, sel);
            fr.w = __builtin_amdgcn_perm(U2.w, U2.z, sel);
            bf16x8 as = __builtin_bit_cast(bf16x8, fr);
            #pragma unroll
            for (int dt = 0; dt < 4; ++dt) {
                bf16x8 bv = *(const bf16x8*)&VT[ks][dt * 16 + col][quad * 8];
                oacc[dt] = MFMA(as, bv, oacc[dt]);
            }
        }
    }

    #pragma unroll
    for (int r = 0; r < 4; ++r) {
        float v = racc[r];
        v += __shfl_xor(v, 1); v += __shfl_xor(v, 2);
        v += __shfl_xor(v, 4); v += __shfl_xor(v, 8);
        if (col == 0) rowz[w * 16 + quad * 4 + r] = v;
    }
    __syncthreads();
    #pragma unroll
    for (int r = 0; r < 4; ++r) {
        const int nl = w * 16 + quad * 4 + r;
        const float z = 1.f / (rowz[nl] + EPS);
        #pragma unroll
        for (int dt = 0; dt < 4; ++dt)
            attnb[(size_t)(b * NP + n0 + nl) * DIM + h * HD + dt * 16 + col] =
                f2b(oacc[dt][r] * z);
    }
}

// --------------------------------------------------------------------------
// gemm2: out = attnb @ WoutT^T + b_out (fp32). 64x64 tiles, BK=64, grid
// 768 = 3.0 even rounds (was 384 = 1.5, half the CUs idle in round 2).
// --------------------------------------------------------------------------
__global__ __launch_bounds__(256) void k_gemm2(const unsigned short* __restrict__ A,
                                               const unsigned short* __restrict__ Bt,
                                               const float* __restrict__ bias,
                                               float* __restrict__ C) {
    __shared__ unsigned short As[2][64][32];
    __shared__ unsigned short Bs[2][64][32];
    const int tid = threadIdx.x, w = tid >> 6, l = tid & 63;
    const int bid = blockIdx.x;                 // 768 blocks
    const int mstrip = (bid & 7) * 8 + ((bid >> 3) & 7);   // [0,64)
    const int nstrip = bid >> 6;                           // [0,12)
    const int m0 = mstrip * 64, n0 = nstrip * 64;
    const int wm = (w & 1) * 32, wn = (w >> 1) * 32;
    const int quad = l >> 4, col = l & 15;
    const int lr = l >> 2, lc = (l & 3) * 8;

    f32x4 acc[2][2] = {};
    for (int k0 = 0; k0 < DIM; k0 += 64) {
        #pragma unroll
        for (int hh = 0; hh < 2; ++hh) {
            gld16(A + (size_t)(m0 + w * 16 + lr) * DIM + k0 + hh * 32 + lc, &As[hh][w * 16][0]);
            gld16(Bt + (size_t)(n0 + w * 16 + lr) * DIM + k0 + hh * 32 + lc, &Bs[hh][w * 16][0]);
        }
        __syncthreads();
        #pragma unroll
        for (int hh = 0; hh < 2; ++hh) {
            bf16x8 a[2], b[2];
            #pragma unroll
            for (int i = 0; i < 2; ++i) a[i] = *(const bf16x8*)&As[hh][wm + i * 16 + col][quad * 8];
            #pragma unroll
            for (int j = 0; j < 2; ++j) b[j] = *(const bf16x8*)&Bs[hh][wn + j * 16 + col][quad * 8];
            #pragma unroll
            for (int i = 0; i < 2; ++i)
                #pragma unroll
                for (int j = 0; j < 2; ++j)
                    acc[i][j] = MFMA(a[i], b[j], acc[i][j]);
        }
        __syncthreads();
    }
    #pragma unroll
    for (int i = 0; i < 2; ++i)
        #pragma unroll
        for (int j = 0; j < 2; ++j) {
            const int n = n0 + wn + j * 16 + col;
            #pragma unroll
            for (int r = 0; r < 4; ++r) {
                const int m = m0 + wm + i * 16 + quad * 4 + r;
                C[(size_t)m * DIM + n] = acc[i][j][r] + bias[n];
            }
        }
}

// --------------------------------------------------------------------------
extern "C" void kernel_launch(void* const* d_in, const int* in_sizes, int n_in,
                              void* d_out, int out_size, void* d_ws, size_t ws_size,
                              hipStream_t stream) {
    (void)in_sizes; (void)n_in; (void)out_size; (void)ws_size;
    const float* x     = (const float*)d_in[0];
    const float* W_qkv = (const float*)d_in[1];
    const float* W_out = (const float*)d_in[2];
    const float* b_out = (const float*)d_in[3];
    const float* mask  = (const float*)d_in[4];
    float* out = (float*)d_out;

    unsigned short* p = (unsigned short*)d_ws;
    unsigned short* WqkvT = p; p += (size_t)TQ * DIM;
    unsigned short* WoutT = p; p += (size_t)DIM * DIM;
    unsigned short* M2    = p; p += (size_t)NP * NP;
    unsigned short* T     = p; p += (size_t)3 * 48 * HD * NP;
    unsigned short* q2    = p; p += (size_t)2 * 48 * NP * HD;
    unsigned short* attnb = p; p += (size_t)4096 * DIM;

    k_prep<<<dim3(832), 256, 0, stream>>>(W_qkv, W_out, mask, WqkvT, WoutT, M2);
    k_gemm1<<<dim3(576), 512, 0, stream>>>(x, WqkvT, T);
    k_graphmix<<<dim3(NP / 64, 48), 256, 0, stream>>>(M2, T, q2);
    k_attn<<<dim3(NP / 64, 48), 256, 0, stream>>>(q2, T, mask, attnb);
    k_gemm2<<<dim3(768), 256, 0, stream>>>(attnb, WoutT, b_out, out);
}